// Round 5
// baseline (647.297 us; speedup 1.0000x reference)
//
#include <hip/hip_runtime.h>

typedef unsigned short u16;
typedef __bf16 bf16x8 __attribute__((ext_vector_type(8)));
typedef float f32x4 __attribute__((ext_vector_type(4)));
typedef unsigned short us8 __attribute__((ext_vector_type(8)));

__device__ inline u16 f2bf(float f) {
    union { float f; unsigned u; } v; v.f = f;
    unsigned r = v.u + 0x7FFFu + ((v.u >> 16) & 1u);
    return (u16)(r >> 16);
}
__device__ inline float bf2f(u16 h) {
    union { unsigned u; float f; } v; v.u = ((unsigned)h) << 16;
    return v.f;
}
__device__ inline f32x4 mfma16(bf16x8 a, bf16x8 b, f32x4 c) {
    return __builtin_amdgcn_mfma_f32_16x16x32_bf16(a, b, c, 0, 0, 0);
}
__device__ inline void gload_lds16(const u16* g, u16* l) {
    __builtin_amdgcn_global_load_lds(
        (const __attribute__((address_space(1))) void*)g,
        (__attribute__((address_space(3))) void*)l, 16, 0, 0);
}

// ---------------------------------------------------------------------------
// One-shot pack: x, Wq, Wk, Wv, Wo -> bf16; bias concat. Block-range dispatch.
// ---------------------------------------------------------------------------
__global__ __launch_bounds__(256)
void pack_all(const float* __restrict__ x,  const float* __restrict__ Wq,
              const float* __restrict__ Wk, const float* __restrict__ Wv,
              const float* __restrict__ Wo, const float* __restrict__ bq,
              const float* __restrict__ bk, const float* __restrict__ bv,
              u16* __restrict__ xb, u16* __restrict__ Wqkvb,
              u16* __restrict__ Wob, float* __restrict__ bqkv)
{
    int blk = blockIdx.x;
    if (blk == 9216) {
        for (int k = threadIdx.x; k < 3072; k += 256) {
            float v;
            if (k < 2048) v = bq[k];
            else if (k < 2560) v = bk[k - 2048];
            else v = bv[k - 2560];
            bqkv[k] = v;
        }
        return;
    }
    const float* src; u16* dst; size_t off;
    if (blk < 4096)      { src = x;  dst = xb;                 off = (size_t)blk * 2048; }
    else if (blk < 6144) { src = Wq; dst = Wqkvb;              off = (size_t)(blk - 4096) * 2048; }
    else if (blk < 6656) { src = Wk; dst = Wqkvb + 4194304;    off = (size_t)(blk - 6144) * 2048; }
    else if (blk < 7168) { src = Wv; dst = Wqkvb + 5242880;    off = (size_t)(blk - 6656) * 2048; }
    else                 { src = Wo; dst = Wob;                off = (size_t)(blk - 7168) * 2048; }
    size_t i = off + (size_t)threadIdx.x * 8;
    float4 v0 = *(const float4*)(src + i);
    float4 v1 = *(const float4*)(src + i + 4);
    us8 w;
    w[0] = f2bf(v0.x); w[1] = f2bf(v0.y); w[2] = f2bf(v0.z); w[3] = f2bf(v0.w);
    w[4] = f2bf(v1.x); w[5] = f2bf(v1.y); w[6] = f2bf(v1.z); w[7] = f2bf(v1.w);
    *(us8*)(dst + i) = w;
}

// ---------------------------------------------------------------------------
// Shared K-loop (m97 structure: 128x128 tile, BK=32, global_load_lds w=16,
// XOR-swizzled LDS columns).
// ---------------------------------------------------------------------------
#define GEMM_PROLOGUE(Aptr, Bptr, Kdim)                                        \
    __shared__ u16 As[128 * 32];                                               \
    __shared__ u16 Bs[128 * 32];                                               \
    const int tid = threadIdx.x;                                               \
    const int lane = tid & 63;                                                 \
    const int wv = tid >> 6;                                                   \
    const int wr = wv >> 1, wc = wv & 1;                                       \
    const long m0 = (long)blockIdx.y * 128;                                    \
    const long n0 = (long)blockIdx.x * 128;                                    \
    const int cc = lane & 15, qq = lane >> 4;                                  \
    const int srow = (2 * wv) * 16 + (lane >> 2);                              \
    const int gcol = (((lane & 3) ^ ((lane >> 3) & 3)) << 3);                  \
    const u16* Ag0 = Aptr + (m0 + srow) * (long)Kdim + gcol;                   \
    const u16* Ag1 = Aptr + (m0 + srow + 16) * (long)Kdim + gcol;              \
    const u16* Bg0 = Bptr + (n0 + srow) * (long)Kdim + gcol;                   \
    const u16* Bg1 = Bptr + (n0 + srow + 16) * (long)Kdim + gcol;              \
    u16* AsW0 = &As[(2 * wv) * 512];                                           \
    u16* AsW1 = AsW0 + 512;                                                    \
    u16* BsW0 = &Bs[(2 * wv) * 512];                                           \
    u16* BsW1 = BsW0 + 512;                                                    \
    const int csw = (qq ^ ((cc >> 1) & 3)) << 3;                               \
    f32x4 acc[4][4];                                                           \
    _Pragma("unroll") for (int i = 0; i < 4; i++)                              \
        _Pragma("unroll") for (int j = 0; j < 4; j++)                          \
            acc[i][j] = (f32x4){0.f, 0.f, 0.f, 0.f};                           \
    for (int k0 = 0; k0 < Kdim; k0 += 32) {                                    \
        gload_lds16(Ag0 + k0, AsW0);                                           \
        gload_lds16(Ag1 + k0, AsW1);                                           \
        gload_lds16(Bg0 + k0, BsW0);                                           \
        gload_lds16(Bg1 + k0, BsW1);                                           \
        __syncthreads();                                                       \
        bf16x8 af[4], bfr[4];                                                  \
        _Pragma("unroll") for (int i = 0; i < 4; i++)                          \
            af[i] = *(const bf16x8*)&As[(wr * 64 + i * 16 + cc) * 32 + csw];   \
        _Pragma("unroll") for (int j = 0; j < 4; j++)                          \
            bfr[j] = *(const bf16x8*)&Bs[(wc * 64 + j * 16 + cc) * 32 + csw];  \
        _Pragma("unroll") for (int i = 0; i < 4; i++)                          \
            _Pragma("unroll") for (int j = 0; j < 4; j++)                      \
                acc[i][j] = mfma16(af[i], bfr[j], acc[i][j]);                  \
        __syncthreads();                                                       \
    }

// ---------------------------------------------------------------------------
// Fused QKV projection + YaRN RoPE + head relayout, with LDS-staged
// COALESCED epilogue stores (the round-4 scattered 2B stores caused ~100x
// HBM write amplification).
//   cols [0,2048)    -> rope -> Qb  [B,32,S,64]
//   cols [2048,2560) -> rope -> Kb  [B,8,S,64]
//   cols [2560,3072) ->         Vtmp [B*S,512]
// Epilogue: per wave, 2 chunks of 32 rows; values -> private 4KB LDS tile
// (reusing As/Bs) -> us8 readback -> 1KB-contiguous global stores.
// ---------------------------------------------------------------------------
__global__ __launch_bounds__(256, 2)
void gemm_qkv(const u16* __restrict__ A, const u16* __restrict__ B,
              const float* __restrict__ bias, const int* __restrict__ pid,
              u16* __restrict__ Qb, u16* __restrict__ Kb, u16* __restrict__ Vtmp)
{
    GEMM_PROLOGUE(A, B, 2048)

    u16* pool = (wv < 2) ? &As[wv * 2048] : &Bs[(wv - 2) * 2048];
    const int reg = (n0 < 2048) ? 0 : (n0 < 2560 ? 1 : 2);

    if (reg < 2) {
        const int nheads = reg ? 8 : 32;
        const int hidx = (int)(n0 >> 6) + wc - (reg ? 32 : 0);
        u16* Out = reg ? Kb : Qb;
        // per-j rope frequency and biases (d = j*16+cc, 0..31)
        float effs[2], bL[2], bH[2];
#pragma unroll
        for (int j = 0; j < 2; j++) {
            const int d = j * 16 + cc;
            float ex = (float)d * (1.0f / 32.0f);
            float freq = powf(10000.0f, -ex);
            float wl = 6.2831853071795864f / freq;
            float tt = (wl - 32.0f) * (1.0f / 992.0f);
            tt = fminf(fmaxf(tt, 0.0f), 1.0f);
            float eff = freq * (1.0f - tt) + 0.25f * freq * tt;
            effs[j] = eff * 1.1386294361119891f;
            const long colL = n0 + wc * 64 + j * 16 + cc;
            bL[j] = bias[colL];
            bH[j] = bias[colL + 32];
        }
#pragma unroll
        for (int chunk = 0; chunk < 2; ++chunk) {
#pragma unroll
            for (int ii = 0; ii < 2; ++ii) {
                int i = chunk * 2 + ii;
#pragma unroll
                for (int r2 = 0; r2 < 4; ++r2) {
                    int lr = ii * 16 + qq * 4 + r2;
                    long m = m0 + wr * 64 + chunk * 32 + lr;
                    int pos = pid[m];
#pragma unroll
                    for (int j = 0; j < 2; ++j) {
                        float ang = (float)pos * effs[j];
                        float sv = sinf(ang), cv = cosf(ang);
                        float x1 = acc[i][j][r2] + bL[j];
                        float x2 = acc[i][j + 2][r2] + bH[j];
                        int d = j * 16 + cc;
                        pool[lr * 64 + d]      = f2bf(x1 * cv - x2 * sv);
                        pool[lr * 64 + d + 32] = f2bf(x2 * cv + x1 * sv);
                    }
                }
            }
            __syncthreads();
#pragma unroll
            for (int t = 0; t < 4; ++t) {
                int lr = t * 8 + (lane >> 3);
                int d8 = (lane & 7) * 8;
                us8 v = *(const us8*)&pool[lr * 64 + d8];
                long m = m0 + wr * 64 + chunk * 32 + lr;
                int bb = (int)(m >> 11), ss = (int)(m & 2047);
                *(us8*)(Out + ((size_t)(bb * nheads + hidx) * 2048 + ss) * 64 + d8) = v;
            }
            __syncthreads();
        }
    } else {
        const long vcol0 = n0 - 2560 + wc * 64;
        float bj[4];
#pragma unroll
        for (int j = 0; j < 4; j++) bj[j] = bias[n0 + wc * 64 + j * 16 + cc];
#pragma unroll
        for (int chunk = 0; chunk < 2; ++chunk) {
#pragma unroll
            for (int ii = 0; ii < 2; ++ii) {
                int i = chunk * 2 + ii;
#pragma unroll
                for (int r2 = 0; r2 < 4; ++r2) {
                    int lr = ii * 16 + qq * 4 + r2;
#pragma unroll
                    for (int j = 0; j < 4; ++j)
                        pool[lr * 64 + j * 16 + cc] = f2bf(acc[i][j][r2] + bj[j]);
                }
            }
            __syncthreads();
#pragma unroll
            for (int t = 0; t < 4; ++t) {
                int lr = t * 8 + (lane >> 3);
                int d8 = (lane & 7) * 8;
                us8 v = *(const us8*)&pool[lr * 64 + d8];
                long m = m0 + wr * 64 + chunk * 32 + lr;
                *(us8*)(Vtmp + (size_t)m * 512 + vcol0 + d8) = v;
            }
            __syncthreads();
        }
    }
}

// ---------------------------------------------------------------------------
// Output projection: fp32 out + bias (row-contiguous stores, unchanged).
// ---------------------------------------------------------------------------
__global__ __launch_bounds__(256, 2)
void gemm_out(const u16* __restrict__ A, const u16* __restrict__ B,
              const float* __restrict__ bias, float* __restrict__ Y)
{
    GEMM_PROLOGUE(A, B, 2048)
    const long N = 2048;
#pragma unroll
    for (int i = 0; i < 4; i++) {
#pragma unroll
        for (int j = 0; j < 4; j++) {
            long row = m0 + wr * 64 + i * 16 + qq * 4;
            long col = n0 + wc * 64 + j * 16 + cc;
            float bv = bias[col];
#pragma unroll
            for (int r2 = 0; r2 < 4; r2++)
                Y[(row + r2) * N + col] = acc[i][j][r2] + bv;
        }
    }
}

// ---------------------------------------------------------------------------
// V: bf16 [B*S, 512] -> bf16 transposed [B*NKV, 64, S]
// ---------------------------------------------------------------------------
__global__ __launch_bounds__(256)
void v_transpose(const u16* __restrict__ Vt, u16* __restrict__ VbT)
{
    __shared__ u16 tile[64][66];
    int s0 = blockIdx.x * 64;
    int bkv = blockIdx.y;
    int b = bkv >> 3, kv = bkv & 7;
    int t = threadIdx.x;
#pragma unroll
    for (int it = 0; it < 16; ++it) {
        int idx = t + it * 256;
        int s = idx >> 6, d = idx & 63;
        tile[s][d] = Vt[((size_t)(b * 2048 + s0 + s)) * 512 + kv * 64 + d];
    }
    __syncthreads();
#pragma unroll
    for (int it = 0; it < 16; ++it) {
        int idx = t + it * 256;
        int d = idx >> 6, s = idx & 63;
        VbT[((size_t)(bkv * 64 + d)) * 2048 + s0 + s] = tile[s][d];
    }
}

// ---------------------------------------------------------------------------
// Sliding-window attention, 64-query tiles (unchanged).
// ---------------------------------------------------------------------------
__global__ __launch_bounds__(256, 2)
void attn_win(const u16* __restrict__ Qb, const u16* __restrict__ Kb,
              const u16* __restrict__ VbT, const float* __restrict__ sinks,
              u16* __restrict__ Ctx)
{
    __shared__ u16 Ks[192 * 72];
    __shared__ u16 Vs[64 * 200];
    __shared__ u16 Pb[4 * 16 * 200];
    const int S = 2048;
    const int tid = threadIdx.x;
    const int lane = tid & 63;
    const int w = tid >> 6;
    const int cc = lane & 15, qq = lane >> 4;
    const int blk = blockIdx.x;
    const int qt = blk & 31;
    const int bkv = blk >> 5;
    const int b = bkv >> 3;
    const int q0 = qt * 64;
    const int ks0 = q0 - 128;
    const int h = (bkv & 7) * 4 + w;

    const u16* KbBase = Kb + (size_t)bkv * S * 64;
#pragma unroll
    for (int it = 0; it < 6; ++it) {
        int c = tid + it * 256;
        int kk = c >> 3, c8 = (c & 7) << 3;
        int sk = ks0 + kk;
        us8 v = {0, 0, 0, 0, 0, 0, 0, 0};
        if (sk >= 0) v = *(const us8*)(KbBase + (size_t)sk * 64 + c8);
        *(us8*)&Ks[kk * 72 + c8] = v;
    }
    const u16* VtBase = VbT + (size_t)bkv * 64 * S;
#pragma unroll
    for (int it = 0; it < 6; ++it) {
        int c = tid + it * 256;
        int d = c / 24, kc = c % 24;
        int kk0 = kc << 3;
        int sk = ks0 + kk0;
        us8 v = {0, 0, 0, 0, 0, 0, 0, 0};
        if (sk >= 0) v = *(const us8*)(VtBase + (size_t)d * S + sk);
        *(us8*)&Vs[d * 200 + kk0] = v;
    }
    __syncthreads();

    const float sinkv = sinks[h];
    u16* Pw = &Pb[w * 3200];
    const u16* Qbase = Qb + ((size_t)(b * 32 + h) * S + q0) * 64;

    for (int i = 0; i < 4; ++i) {
        const u16* Qrow = Qbase + (size_t)(i * 16 + cc) * 64;
        bf16x8 aq0 = *(const bf16x8*)(Qrow + qq * 8);
        bf16x8 aq1 = *(const bf16x8*)(Qrow + 32 + qq * 8);

        f32x4 sc[12];
#pragma unroll
        for (int j = 0; j < 12; j++) sc[j] = (f32x4){0.f, 0.f, 0.f, 0.f};
#pragma unroll
        for (int j = 0; j < 12; j++) {
            bf16x8 b0 = *(const bf16x8*)&Ks[(j * 16 + cc) * 72 + qq * 8];
            bf16x8 b1 = *(const bf16x8*)&Ks[(j * 16 + cc) * 72 + 32 + qq * 8];
            sc[j] = mfma16(aq0, b0, sc[j]);
            sc[j] = mfma16(aq1, b1, sc[j]);
        }

#pragma unroll
        for (int r = 0; r < 4; ++r) {
            int qi = i * 16 + qq * 4 + r;
            float sval[12];
            float mx = -3.0e38f;
#pragma unroll
            for (int j = 0; j < 12; j++) {
                int kk = j * 16 + cc;
                float s = sc[j][r] * 0.125f;
                bool ok = (kk > qi) && (kk <= qi + 128) && (ks0 + kk >= 0);
                s = ok ? s : -3.0e38f;
                sval[j] = s;
                mx = fmaxf(mx, s);
            }
#pragma unroll
            for (int off = 1; off < 16; off <<= 1) mx = fmaxf(mx, __shfl_xor(mx, off));
            mx = fmaxf(mx, sinkv);
            float sum = 0.f;
#pragma unroll
            for (int j = 0; j < 12; j++) {
                float p = __expf(sval[j] - mx);
                sval[j] = p;
                sum += p;
            }
#pragma unroll
            for (int off = 1; off < 16; off <<= 1) sum += __shfl_xor(sum, off);
            float rden = 1.0f / (sum + __expf(sinkv - mx));
#pragma unroll
            for (int j = 0; j < 12; j++)
                Pw[(qq * 4 + r) * 200 + j * 16 + cc] = f2bf(sval[j] * rden);
        }

        f32x4 o[4];
#pragma unroll
        for (int jt = 0; jt < 4; jt++) o[jt] = (f32x4){0.f, 0.f, 0.f, 0.f};
#pragma unroll
        for (int ks = 0; ks < 6; ks++) {
            bf16x8 ap = *(const bf16x8*)&Pw[cc * 200 + ks * 32 + qq * 8];
#pragma unroll
            for (int jt = 0; jt < 4; jt++) {
                bf16x8 bv = *(const bf16x8*)&Vs[(jt * 16 + cc) * 200 + ks * 32 + qq * 8];
                o[jt] = mfma16(ap, bv, o[jt]);
            }
        }
#pragma unroll
        for (int jt = 0; jt < 4; jt++) {
#pragma unroll
            for (int r = 0; r < 4; r++) {
                size_t off = ((size_t)(b * S + q0 + i * 16 + qq * 4 + r)) * 2048
                           + h * 64 + jt * 16 + cc;
                Ctx[off] = f2bf(o[jt][r]);
            }
        }
    }
}

// ---------------------------------------------------------------------------
extern "C" void kernel_launch(void* const* d_in, const int* in_sizes, int n_in,
                              void* d_out, int out_size, void* d_ws, size_t ws_size,
                              hipStream_t stream)
{
    const float* x    = (const float*)d_in[0];
    const float* Wq   = (const float*)d_in[1];
    const float* bq   = (const float*)d_in[2];
    const float* Wk   = (const float*)d_in[3];
    const float* bk   = (const float*)d_in[4];
    const float* Wv   = (const float*)d_in[5];
    const float* bv   = (const float*)d_in[6];
    const float* Wo   = (const float*)d_in[7];
    const float* bo   = (const float*)d_in[8];
    const float* sinks = (const float*)d_in[9];
    const int*   pid  = (const int*)d_in[10];
    float* out = (float*)d_out;

    char* ws = (char*)d_ws;
    u16*   Wqkvb = (u16*)ws;                         // 12,582,912 B
    u16*   Wob   = (u16*)(ws + 12582912);            //  8,388,608 B
    u16*   xb    = (u16*)(ws + 20971520);            // 16,777,216 B (then Ctx)
    u16*   Ctx   = xb;
    u16*   Qb    = (u16*)(ws + 37748736);            // 16,777,216 B
    u16*   Kb    = (u16*)(ws + 54525952);            //  4,194,304 B
    u16*   Vtmp  = (u16*)(ws + 58720256);            //  4,194,304 B
    u16*   VbT   = (u16*)(ws + 62914560);            //  4,194,304 B
    float* bqkv  = (float*)(ws + 67108864);          //     12,288 B

    pack_all<<<9217, 256, 0, stream>>>(x, Wq, Wk, Wv, Wo, bq, bk, bv,
                                       xb, Wqkvb, Wob, bqkv);

    gemm_qkv<<<dim3(24, 32), 256, 0, stream>>>(xb, Wqkvb, bqkv, pid, Qb, Kb, Vtmp);

    v_transpose<<<dim3(32, 16), 256, 0, stream>>>(Vtmp, VbT);

    attn_win<<<512, 256, 0, stream>>>(Qb, Kb, VbT, sinks, Ctx);

    gemm_out<<<dim3(16, 32), 256, 0, stream>>>(Ctx, Wob, bo, out);
}

// Round 6
// 264.822 us; speedup vs baseline: 2.4443x; 2.4443x over previous
//
#include <hip/hip_runtime.h>

typedef unsigned short u16;
typedef __bf16 bf16x8 __attribute__((ext_vector_type(8)));
typedef float f32x4 __attribute__((ext_vector_type(4)));
typedef unsigned short us8 __attribute__((ext_vector_type(8)));

__device__ inline u16 f2bf(float f) {
    union { float f; unsigned u; } v; v.f = f;
    unsigned r = v.u + 0x7FFFu + ((v.u >> 16) & 1u);
    return (u16)(r >> 16);
}
__device__ inline float bf2f(u16 h) {
    union { unsigned u; float f; } v; v.u = ((unsigned)h) << 16;
    return v.f;
}
__device__ inline f32x4 mfma16(bf16x8 a, bf16x8 b, f32x4 c) {
    return __builtin_amdgcn_mfma_f32_16x16x32_bf16(a, b, c, 0, 0, 0);
}
__device__ inline void gload_lds16(const u16* g, u16* l) {
    __builtin_amdgcn_global_load_lds(
        (const __attribute__((address_space(1))) void*)g,
        (__attribute__((address_space(3))) void*)l, 16, 0, 0);
}
union frag_cast { us8 u; bf16x8 b; };

// ---------------------------------------------------------------------------
// One-shot pack: x, Wq, Wk, Wv, Wo -> bf16; bias concat; YaRN sincos table
// tab[pos][d] = (cos, sin) of pos*eff(d)*conc, pos<4096, d<32.
// ---------------------------------------------------------------------------
__global__ __launch_bounds__(256)
void pack_all(const float* __restrict__ x,  const float* __restrict__ Wq,
              const float* __restrict__ Wk, const float* __restrict__ Wv,
              const float* __restrict__ Wo, const float* __restrict__ bq,
              const float* __restrict__ bk, const float* __restrict__ bv,
              u16* __restrict__ xb, u16* __restrict__ Wqkvb,
              u16* __restrict__ Wob, float* __restrict__ bqkv,
              float2* __restrict__ tab)
{
    int blk = blockIdx.x;
    if (blk >= 9217) {                       // sincos table: 512 blocks
        int idx = (blk - 9217) * 256 + threadIdx.x;   // = pos*32 + d
        int d = idx & 31, pos = idx >> 5;
        float ex = (float)d * (1.0f / 32.0f);
        float freq = powf(10000.0f, -ex);
        float wl = 6.2831853071795864f / freq;
        float tt = fminf(fmaxf((wl - 32.0f) * (1.0f / 992.0f), 0.0f), 1.0f);
        float eff = (freq * (1.0f - tt) + 0.25f * freq * tt) * 1.1386294361119891f;
        float ang = (float)pos * eff;
        tab[idx] = make_float2(cosf(ang), sinf(ang));
        return;
    }
    if (blk == 9216) {
        for (int k = threadIdx.x; k < 3072; k += 256) {
            float v;
            if (k < 2048) v = bq[k];
            else if (k < 2560) v = bk[k - 2048];
            else v = bv[k - 2560];
            bqkv[k] = v;
        }
        return;
    }
    const float* src; u16* dst; size_t off;
    if (blk < 4096)      { src = x;  dst = xb;                 off = (size_t)blk * 2048; }
    else if (blk < 6144) { src = Wq; dst = Wqkvb;              off = (size_t)(blk - 4096) * 2048; }
    else if (blk < 6656) { src = Wk; dst = Wqkvb + 4194304;    off = (size_t)(blk - 6144) * 2048; }
    else if (blk < 7168) { src = Wv; dst = Wqkvb + 5242880;    off = (size_t)(blk - 6656) * 2048; }
    else                 { src = Wo; dst = Wob;                off = (size_t)(blk - 7168) * 2048; }
    size_t i = off + (size_t)threadIdx.x * 8;
    float4 v0 = *(const float4*)(src + i);
    float4 v1 = *(const float4*)(src + i + 4);
    us8 w;
    w[0] = f2bf(v0.x); w[1] = f2bf(v0.y); w[2] = f2bf(v0.z); w[3] = f2bf(v0.w);
    w[4] = f2bf(v1.x); w[5] = f2bf(v1.y); w[6] = f2bf(v1.z); w[7] = f2bf(v1.w);
    *(us8*)(dst + i) = w;
}

// ---------------------------------------------------------------------------
// GEMM: Y[M,N] = A[M,K] * B[N,K]^T + bias[N]  (round-3 proven kernel,
// verbatim).  A/B bf16, out fp32 or bf16 row-major.
// ---------------------------------------------------------------------------
template<int OUT_BF16>
__global__ __launch_bounds__(256, 2)
void gemm_bb(const u16* __restrict__ A, const u16* __restrict__ B,
             const float* __restrict__ bias, void* __restrict__ Yv,
             int M, int N, int K)
{
    __shared__ u16 As[128 * 32];
    __shared__ u16 Bs[128 * 32];
    const int tid = threadIdx.x;
    const int lane = tid & 63;
    const int wv = tid >> 6;
    const int wr = wv >> 1, wc = wv & 1;
    const long m0 = (long)blockIdx.y * 128;
    const long n0 = (long)blockIdx.x * 128;
    const int cc = lane & 15, qq = lane >> 4;

    const int srow = (2 * wv) * 16 + (lane >> 2);
    const int gcol = (((lane & 3) ^ ((lane >> 3) & 3)) << 3);
    const u16* Ag0 = A + (m0 + srow) * (long)K + gcol;
    const u16* Ag1 = A + (m0 + srow + 16) * (long)K + gcol;
    const u16* Bg0 = B + (n0 + srow) * (long)K + gcol;
    const u16* Bg1 = B + (n0 + srow + 16) * (long)K + gcol;
    u16* AsW0 = &As[(2 * wv) * 512];
    u16* AsW1 = AsW0 + 512;
    u16* BsW0 = &Bs[(2 * wv) * 512];
    u16* BsW1 = BsW0 + 512;

    const int csw = (qq ^ ((cc >> 1) & 3)) << 3;

    f32x4 acc[4][4];
#pragma unroll
    for (int i = 0; i < 4; i++)
#pragma unroll
        for (int j = 0; j < 4; j++) acc[i][j] = (f32x4){0.f, 0.f, 0.f, 0.f};

    for (int k0 = 0; k0 < K; k0 += 32) {
        gload_lds16(Ag0 + k0, AsW0);
        gload_lds16(Ag1 + k0, AsW1);
        gload_lds16(Bg0 + k0, BsW0);
        gload_lds16(Bg1 + k0, BsW1);
        __syncthreads();
        bf16x8 af[4], bfr[4];
#pragma unroll
        for (int i = 0; i < 4; i++)
            af[i] = *(const bf16x8*)&As[(wr * 64 + i * 16 + cc) * 32 + csw];
#pragma unroll
        for (int j = 0; j < 4; j++)
            bfr[j] = *(const bf16x8*)&Bs[(wc * 64 + j * 16 + cc) * 32 + csw];
#pragma unroll
        for (int i = 0; i < 4; i++)
#pragma unroll
            for (int j = 0; j < 4; j++)
                acc[i][j] = mfma16(af[i], bfr[j], acc[i][j]);
        __syncthreads();
    }

#pragma unroll
    for (int i = 0; i < 4; i++) {
#pragma unroll
        for (int j = 0; j < 4; j++) {
            long row = m0 + wr * 64 + i * 16 + qq * 4;
            long col = n0 + wc * 64 + j * 16 + cc;
            float bv = bias[col];
#pragma unroll
            for (int r2 = 0; r2 < 4; r2++) {
                float v = acc[i][j][r2] + bv;
                if (OUT_BF16)
                    ((u16*)Yv)[(row + r2) * (long)N + col] = f2bf(v);
                else
                    ((float*)Yv)[(row + r2) * (long)N + col] = v;
            }
        }
    }
}

// ---------------------------------------------------------------------------
// V: bf16 [B*S, 3072] (cols 2560..3071) -> bf16 transposed [B*NKV, 64, S]
// (round-3 proven kernel, verbatim)
// ---------------------------------------------------------------------------
__global__ __launch_bounds__(256)
void v_transpose(const u16* __restrict__ Vt, u16* __restrict__ VbT)
{
    __shared__ u16 tile[64][66];
    int s0 = blockIdx.x * 64;
    int bkv = blockIdx.y;
    int b = bkv >> 3, kv = bkv & 7;
    int t = threadIdx.x;
#pragma unroll
    for (int it = 0; it < 16; ++it) {
        int idx = t + it * 256;
        int s = idx >> 6, d = idx & 63;
        tile[s][d] = Vt[((size_t)(b * 2048 + s0 + s)) * 3072 + 2560 + kv * 64 + d];
    }
    __syncthreads();
#pragma unroll
    for (int it = 0; it < 16; ++it) {
        int idx = t + it * 256;
        int d = idx >> 6, s = idx & 63;
        VbT[((size_t)(bkv * 64 + d)) * 2048 + s0 + s] = tile[s][d];
    }
}

// ---------------------------------------------------------------------------
// Sliding-window attention with fused RoPE.
// Q is read from row-major QKVr (cols h*64..h*64+63) and roped in-register
// (the (d, d+32) rope pair sits in the same lane: aq0[jj] / aq1[jj]).
// K (cols 2048+kv*64) is roped during LDS staging via the sincos table.
// V^T from VbT.  Ctx written row-major [B*S, 2048].
// ---------------------------------------------------------------------------
__global__ __launch_bounds__(256, 2)
void attn_win2(const u16* __restrict__ QKVr, const u16* __restrict__ VbT,
               const float2* __restrict__ tab, const int* __restrict__ pid,
               const float* __restrict__ sinks, u16* __restrict__ Ctx)
{
    __shared__ u16 Ks[192 * 72];
    __shared__ u16 Vs[64 * 200];
    __shared__ u16 Pb[4 * 16 * 200];
    const int S = 2048;
    const int tid = threadIdx.x;
    const int lane = tid & 63;
    const int w = tid >> 6;
    const int cc = lane & 15, qq = lane >> 4;
    const int blk = blockIdx.x;
    const int qt = blk & 31;
    const int bkv = blk >> 5;
    const int b = bkv >> 3, kv = bkv & 7;
    const int q0 = qt * 64;
    const int ks0 = q0 - 128;
    const int h = kv * 4 + w;

    // --- stage K with rope: 768 tasks, kk = task>>2, dlo = (task&3)*8
    {
        const int kcol = 2048 + kv * 64;
#pragma unroll
        for (int it = 0; it < 3; ++it) {
            int c = tid + it * 256;
            int kk = c >> 2, dlo = (c & 3) << 3;
            int sk = ks0 + kk;
            us8 lo = {0, 0, 0, 0, 0, 0, 0, 0};
            us8 hi = {0, 0, 0, 0, 0, 0, 0, 0};
            if (sk >= 0) {
                size_t rowoff = (size_t)(b * S + sk) * 3072 + kcol;
                us8 li = *(const us8*)(QKVr + rowoff + dlo);
                us8 hiQ = *(const us8*)(QKVr + rowoff + dlo + 32);
                int pos = pid[b * S + sk];
                const float2* tp = tab + pos * 32 + dlo;
#pragma unroll
                for (int jj = 0; jj < 8; ++jj) {
                    float2 cs = tp[jj];
                    float x1 = bf2f(li[jj]), x2 = bf2f(hiQ[jj]);
                    lo[jj] = f2bf(x1 * cs.x - x2 * cs.y);
                    hi[jj] = f2bf(x2 * cs.x + x1 * cs.y);
                }
            }
            *(us8*)&Ks[kk * 72 + dlo] = lo;
            *(us8*)&Ks[kk * 72 + dlo + 32] = hi;
        }
    }
    // --- stage V^T
    const u16* VtBase = VbT + (size_t)bkv * 64 * S;
#pragma unroll
    for (int it = 0; it < 6; ++it) {
        int c = tid + it * 256;
        int d = c / 24, kc = c % 24;
        int kk0 = kc << 3;
        int sk = ks0 + kk0;
        us8 v = {0, 0, 0, 0, 0, 0, 0, 0};
        if (sk >= 0) v = *(const us8*)(VtBase + (size_t)d * S + sk);
        *(us8*)&Vs[d * 200 + kk0] = v;
    }
    __syncthreads();

    const float sinkv = sinks[h];
    u16* Pw = &Pb[w * 3200];

    for (int i = 0; i < 4; ++i) {
        // Q fragment from row-major QKVr + in-register rope
        int m = b * S + q0 + i * 16 + cc;
        const u16* Qrow = QKVr + (size_t)m * 3072 + h * 64;
        us8 qlo = *(const us8*)(Qrow + qq * 8);
        us8 qhi = *(const us8*)(Qrow + 32 + qq * 8);
        int pos = pid[m];
        const float2* tp = tab + pos * 32 + qq * 8;
        frag_cast a0, a1;
#pragma unroll
        for (int jj = 0; jj < 8; ++jj) {
            float2 cs = tp[jj];
            float x1 = bf2f(qlo[jj]), x2 = bf2f(qhi[jj]);
            a0.u[jj] = f2bf(x1 * cs.x - x2 * cs.y);
            a1.u[jj] = f2bf(x2 * cs.x + x1 * cs.y);
        }
        bf16x8 aq0 = a0.b, aq1 = a1.b;

        f32x4 sc[12];
#pragma unroll
        for (int j = 0; j < 12; j++) sc[j] = (f32x4){0.f, 0.f, 0.f, 0.f};
#pragma unroll
        for (int j = 0; j < 12; j++) {
            bf16x8 b0 = *(const bf16x8*)&Ks[(j * 16 + cc) * 72 + qq * 8];
            bf16x8 b1 = *(const bf16x8*)&Ks[(j * 16 + cc) * 72 + 32 + qq * 8];
            sc[j] = mfma16(aq0, b0, sc[j]);
            sc[j] = mfma16(aq1, b1, sc[j]);
        }

#pragma unroll
        for (int r = 0; r < 4; ++r) {
            int qi = i * 16 + qq * 4 + r;
            float sval[12];
            float mx = -3.0e38f;
#pragma unroll
            for (int j = 0; j < 12; j++) {
                int kk = j * 16 + cc;
                float s = sc[j][r] * 0.125f;
                bool ok = (kk > qi) && (kk <= qi + 128) && (ks0 + kk >= 0);
                s = ok ? s : -3.0e38f;
                sval[j] = s;
                mx = fmaxf(mx, s);
            }
#pragma unroll
            for (int off = 1; off < 16; off <<= 1) mx = fmaxf(mx, __shfl_xor(mx, off));
            mx = fmaxf(mx, sinkv);
            float sum = 0.f;
#pragma unroll
            for (int j = 0; j < 12; j++) {
                float p = __expf(sval[j] - mx);
                sval[j] = p;
                sum += p;
            }
#pragma unroll
            for (int off = 1; off < 16; off <<= 1) sum += __shfl_xor(sum, off);
            float rden = 1.0f / (sum + __expf(sinkv - mx));
#pragma unroll
            for (int j = 0; j < 12; j++)
                Pw[(qq * 4 + r) * 200 + j * 16 + cc] = f2bf(sval[j] * rden);
        }

        f32x4 o[4];
#pragma unroll
        for (int jt = 0; jt < 4; jt++) o[jt] = (f32x4){0.f, 0.f, 0.f, 0.f};
#pragma unroll
        for (int ks = 0; ks < 6; ks++) {
            bf16x8 ap = *(const bf16x8*)&Pw[cc * 200 + ks * 32 + qq * 8];
#pragma unroll
            for (int jt = 0; jt < 4; jt++) {
                bf16x8 bv = *(const bf16x8*)&Vs[(jt * 16 + cc) * 200 + ks * 32 + qq * 8];
                o[jt] = mfma16(ap, bv, o[jt]);
            }
        }
#pragma unroll
        for (int jt = 0; jt < 4; jt++) {
#pragma unroll
            for (int r = 0; r < 4; r++) {
                size_t off = ((size_t)(b * S + q0 + i * 16 + qq * 4 + r)) * 2048
                           + h * 64 + jt * 16 + cc;
                Ctx[off] = f2bf(o[jt][r]);
            }
        }
    }
}

// ---------------------------------------------------------------------------
extern "C" void kernel_launch(void* const* d_in, const int* in_sizes, int n_in,
                              void* d_out, int out_size, void* d_ws, size_t ws_size,
                              hipStream_t stream)
{
    const float* x    = (const float*)d_in[0];
    const float* Wq   = (const float*)d_in[1];
    const float* bq   = (const float*)d_in[2];
    const float* Wk   = (const float*)d_in[3];
    const float* bk   = (const float*)d_in[4];
    const float* Wv   = (const float*)d_in[5];
    const float* bv   = (const float*)d_in[6];
    const float* Wo   = (const float*)d_in[7];
    const float* bo   = (const float*)d_in[8];
    const float* sinks = (const float*)d_in[9];
    const int*   pid  = (const int*)d_in[10];
    float* out = (float*)d_out;

    char*  ws    = (char*)d_ws;
    u16*   Wqkvb = (u16*)ws;                         // 12,582,912 B
    u16*   Wob   = (u16*)(ws + 12582912);            //  8,388,608 B
    u16*   xb    = (u16*)(ws + 20971520);            // 16,777,216 B (then Ctx)
    u16*   Ctx   = xb;
    u16*   QKVr  = (u16*)(ws + 37748736);            // 25,165,824 B
    u16*   VbT   = (u16*)(ws + 62914560);            //  4,194,304 B
    float* bqkv  = (float*)(ws + 67108864);          //     12,288 B
    float2* tab  = (float2*)(ws + 67121152);         //  1,048,576 B (total ~68.2 MB)

    pack_all<<<9729, 256, 0, stream>>>(x, Wq, Wk, Wv, Wo, bq, bk, bv,
                                       xb, Wqkvb, Wob, bqkv, tab);

    gemm_bb<1><<<dim3(24, 32), 256, 0, stream>>>(xb, Wqkvb, bqkv, QKVr,
                                                 4096, 3072, 2048);

    v_transpose<<<dim3(32, 16), 256, 0, stream>>>(QKVr, VbT);

    attn_win2<<<512, 256, 0, stream>>>(QKVr, VbT, tab, pid, sinks, Ctx);

    gemm_bb<0><<<dim3(16, 32), 256, 0, stream>>>(Ctx, Wob, bo, out,
                                                 4096, 2048, 2048);
}